// Round 9
// baseline (654.571 us; speedup 1.0000x reference)
//
#include <hip/hip_runtime.h>
#include <hip/hip_bf16.h>
#include <hip/hip_cooperative_groups.h>

namespace cg = cooperative_groups;

// ---------------------------------------------------------------------------
// QuantumImageEncoder R9: ONE cooperative persistent kernel.
//   phase0: block0 builds 16x16 unitary U + zeros stats; blocks>=1 transpose
//           fc1_w -> wT[k*64+o].      grid.sync()
//   main:   grid-stride loop over sample-pairs; R7's proven conv1/conv2/fc
//           phases verbatim (2 samples, 256 thr, 33 KB LDS). grid.sync()
//   tail:   blocks 0..B/256-1 run BN+encoder+U-matvec+measure (R7 quantum).
// Removes all intermediate kernel launches; tests the ~78us non-conv gap.
// ---------------------------------------------------------------------------

#define B_EPS 1e-5f

__global__ __launch_bounds__(256, 4) void mega_kernel(
    const float* __restrict__ x,  const float* __restrict__ c1w,
    const float* __restrict__ c1b, const float* __restrict__ c2w,
    const float* __restrict__ c2b, const float* __restrict__ f1w,
    const float* __restrict__ f1b, const float* __restrict__ f2w,
    const float* __restrict__ f2bias, const float* __restrict__ bn_g,
    const float* __restrict__ bn_b, const float* __restrict__ rl,
    float* __restrict__ out, float* __restrict__ feat,
    float* __restrict__ wT, float* __restrict__ Ug,
    float* __restrict__ stats, int B)
{
    __shared__ union alignas(16) {
        float xin[2][30 * 32];     // padded 28x28, row stride 32, halo ring
        float flat[2][800];        // reused after conv1 (conv2 pooled output)
    } u;
    __shared__ alignas(16) float p1[2][8 * 292];   // [ch][row16][col18]+pad
    __shared__ float w1s[8][9], b1s[8], w2s[16][73], b2s[16];
    __shared__ float part[4][64];                  // fc1 partials per wave
    __shared__ float hs[2][64];                    // fc1 activations
    __shared__ float2 Ush[256];                    // U build / quantum U
    __shared__ float smq[8];                       // quantum reduced stats

    int t = threadIdx.x;
    int w = t >> 6, lane = t & 63;
    int blk = blockIdx.x, nb = gridDim.x;

    // ================= phase 0 =================
    if (blk == 0) {
        // ---- build U = G30*...*G1 into Ush, write Ug; zero 512-float stats
        int r = t >> 4, cc = t & 15;
        Ush[r * 16 + cc] = (r == cc) ? make_float2(1.f, 0.f) : make_float2(0.f, 0.f);
        stats[t] = 0.f;
        stats[t + 256] = 0.f;
        __syncthreads();
        for (int op = 0; op < 30; op++) {
            int kind = op & 3;               // 0=rx,1=ry,2=rz,3=cnot
            float2 cur = Ush[r * 16 + cc];
            float2 nv;
            if (kind == 3) {
                float2 pt = Ush[(r ^ 8) * 16 + cc];
                nv = (r & 1) ? pt : cur;
            } else {
                int m = 8 >> kind;
                float theta = rl[op - (op >> 2)];
                float ch = cosf(0.5f * theta), sh = sinf(0.5f * theta);
                float2 pt = Ush[(r ^ m) * 16 + cc];
                int br = (r & m) ? 1 : 0;
                float2 gc, gp;
                if (kind == 0)      { gc = make_float2(ch, 0.f);           gp = make_float2(0.f, -sh); }
                else if (kind == 1) { gc = make_float2(ch, 0.f);           gp = make_float2(br ? sh : -sh, 0.f); }
                else                { gc = make_float2(ch, br ? sh : -sh); gp = make_float2(0.f, 0.f); }
                nv.x = gc.x*cur.x - gc.y*cur.y + gp.x*pt.x - gp.y*pt.y;
                nv.y = gc.x*cur.y + gc.y*cur.x + gp.x*pt.y + gp.y*pt.x;
            }
            __syncthreads();
            Ush[r * 16 + cc] = nv;
            __syncthreads();
        }
        ((float2*)Ug)[t] = Ush[t];
    } else {
        // ---- transpose fc1_w -> wT[k*64+o], distributed over blocks 1..nb-1
        for (int id = (blk - 1) * 256 + t; id < 784 * 64; id += (nb - 1) * 256) {
            int k = id >> 6, o = id & 63;
            wT[id] = f1w[o * 784 + k];
        }
    }
    // ---- stage conv weights + zero p1 (once; interior rewritten each pair)
    {
        float4 z = make_float4(0.f, 0.f, 0.f, 0.f);
        float4* pz = (float4*)p1;
        for (int i = t; i < 2 * 8 * 292 / 4; i += 256) pz[i] = z;
    }
    if (t < 72) ((float*)w1s)[t] = c1w[t];
    if (t < 8)  b1s[t] = c1b[t];
    for (int i = t; i < 16 * 72; i += 256) w2s[i / 72][i % 72] = c2w[i];
    if (t < 16) b2s[t] = c2b[t];
    __syncthreads();

    __threadfence();
    cg::this_grid().sync();
    __threadfence();

    // ================= main loop: grid-stride over sample-pairs =============
    int npairs = B >> 1;
    for (int pair = blk; pair < npairs; pair += nb) {
        // ---- zero xin (flat aliased it last iteration; halo must be 0)
        {
            float4 z = make_float4(0.f, 0.f, 0.f, 0.f);
            float4* xz = (float4*)u.xin;
            for (int i = t; i < 2 * 30 * 32 / 4; i += 256) xz[i] = z;
        }
        __syncthreads();
        // ---- stage input (2 samples), shifted +1 for the zero halo
        {
            const float4* xg = (const float4*)(x + (size_t)pair * 2 * 784);
            for (int i = t; i < 392; i += 256) {
                float4 v = xg[i];
                int s = i / 196, q = (i - s * 196) * 4;
                float vv[4] = {v.x, v.y, v.z, v.w};
                #pragma unroll
                for (int j = 0; j < 4; j++) {
                    int p = q + j, rr = p / 28, cc2 = p - rr * 28;
                    u.xin[s][(rr + 1) * 32 + cc2 + 1] = vv[j];
                }
            }
        }
        __syncthreads();

        // ---- P2: conv1 + relu + pool -> p1   (wave=(s,h), lane=(ch,colgrp))
        {
            int s = w >> 1, h = w & 1;
            int c = lane >> 3, g = lane & 7;
            if (g < 7) {
                float wk[9];
                #pragma unroll
                for (int q = 0; q < 9; q++) wk[q] = w1s[c][q];
                float bias = b1s[c];
                const float* xb = &u.xin[s][4 * g];
                float* pout = &p1[s][c * 292];
                for (int ii = 0; ii < 7; ii++) {
                    int i = h * 7 + ii;                 // pooled row 0..13
                    const float* r = xb + 2 * i * 32;
                    float rv[4][6];
                    #pragma unroll
                    for (int dr = 0; dr < 4; dr++) {
                        float2 a = *(const float2*)(r + dr * 32);
                        float2 b = *(const float2*)(r + dr * 32 + 2);
                        float2 c2v = *(const float2*)(r + dr * 32 + 4);
                        rv[dr][0] = a.x;  rv[dr][1] = a.y;
                        rv[dr][2] = b.x;  rv[dr][3] = b.y;
                        rv[dr][4] = c2v.x; rv[dr][5] = c2v.y;
                    }
                    float o[2][4];
                    #pragma unroll
                    for (int dr = 0; dr < 2; dr++)
                        #pragma unroll
                        for (int j = 0; j < 4; j++) {
                            float acc = bias;
                            #pragma unroll
                            for (int ky = 0; ky < 3; ky++)
                                #pragma unroll
                                for (int kx = 0; kx < 3; kx++)
                                    acc = fmaf(wk[ky * 3 + kx], rv[dr + ky][j + kx], acc);
                            o[dr][j] = acc;
                        }
                    #pragma unroll
                    for (int jj = 0; jj < 2; jj++) {
                        float m = fmaxf(fmaxf(o[0][2 * jj], o[0][2 * jj + 1]),
                                        fmaxf(o[1][2 * jj], o[1][2 * jj + 1]));
                        pout[(i + 1) * 18 + 1 + 2 * g + jj] = fmaxf(m, 0.f);
                    }
                }
            }
        }
        __syncthreads();

        // ---- P3: conv2 + relu + pool -> u.flat (xin dead now)
        {
            int s = w >> 1, h = w & 1;
            int c2 = lane >> 2, g2 = lane & 3;
            int i0 = h * 4;
            float bias = b2s[c2];
            float acc[4][2][4];
            #pragma unroll
            for (int ii = 0; ii < 4; ii++)
                #pragma unroll
                for (int dr = 0; dr < 2; dr++)
                    #pragma unroll
                    for (int j = 0; j < 4; j++) acc[ii][dr][j] = bias;

            const float* pbase = &p1[s][4 * g2] + i0 * 2 * 18;
            for (int ci = 0; ci < 8; ci++) {
                float wk[9];
                #pragma unroll
                for (int q = 0; q < 9; q++) wk[q] = w2s[c2][ci * 9 + q];
                const float* pc_ = pbase + ci * 292;
                #pragma unroll
                for (int ii = 0; ii < 4; ii++) {
                    if (ii < 3 || h == 0) {
                        float rv[4][6];
                        #pragma unroll
                        for (int dr = 0; dr < 4; dr++) {
                            const float* rp = pc_ + (ii * 2 + dr) * 18;
                            float2 a = *(const float2*)rp;
                            float2 b = *(const float2*)(rp + 2);
                            float2 cc2 = *(const float2*)(rp + 4);
                            rv[dr][0] = a.x;  rv[dr][1] = a.y;
                            rv[dr][2] = b.x;  rv[dr][3] = b.y;
                            rv[dr][4] = cc2.x; rv[dr][5] = cc2.y;
                        }
                        #pragma unroll
                        for (int dr = 0; dr < 2; dr++)
                            #pragma unroll
                            for (int j = 0; j < 4; j++) {
                                float a2 = acc[ii][dr][j];
                                #pragma unroll
                                for (int ky = 0; ky < 3; ky++)
                                    #pragma unroll
                                    for (int kx = 0; kx < 3; kx++)
                                        a2 = fmaf(wk[ky * 3 + kx], rv[dr + ky][j + kx], a2);
                                acc[ii][dr][j] = a2;
                            }
                    }
                }
            }
            #pragma unroll
            for (int ii = 0; ii < 4; ii++) {
                if (ii < 3 || h == 0) {
                    int i = i0 + ii;
                    #pragma unroll
                    for (int jj = 0; jj < 2; jj++) {
                        int pc = 2 * g2 + jj;
                        if (pc < 7) {
                            float m = fmaxf(fmaxf(acc[ii][0][2 * jj], acc[ii][0][2 * jj + 1]),
                                            fmaxf(acc[ii][1][2 * jj], acc[ii][1][2 * jj + 1]));
                            u.flat[s][c2 * 49 + i * 7 + pc] = fmaxf(m, 0.f);
                        }
                    }
                }
            }
        }
        __syncthreads();

        // ---- P5: fc1 partials. wave=(s,k-half); lane=neuron.
        {
            int s = w >> 1, h2 = w & 1;
            const float* fl = u.flat[s];
            const float* wp = wT + lane;
            int k0 = h2 * 392;
            float a0 = 0.f, a1 = 0.f, a2 = 0.f, a3 = 0.f;
            for (int k = k0; k < k0 + 392; k += 4) {
                a0 = fmaf(fl[k    ], wp[(k    ) * 64], a0);
                a1 = fmaf(fl[k + 1], wp[(k + 1) * 64], a1);
                a2 = fmaf(fl[k + 2], wp[(k + 2) * 64], a2);
                a3 = fmaf(fl[k + 3], wp[(k + 3) * 64], a3);
            }
            part[w][lane] = (a0 + a1) + (a2 + a3);
        }
        __syncthreads();

        // ---- P6: combine halves + bias + relu
        if (t < 128) {
            int s = t >> 6, o = t & 63;
            float h = part[2 * s][o] + part[2 * s + 1][o] + f1b[o];
            hs[s][o] = fmaxf(h, 0.f);
        }
        __syncthreads();

        // ---- P7: fc2 + feat + sharded BN stats
        if (t < 8) {
            int s = t >> 2, j = t & 3;
            float a = f2bias[j];
            #pragma unroll
            for (int o = 0; o < 64; o++) a = fmaf(hs[s][o], f2w[j * 64 + o], a);
            feat[((size_t)pair * 2 + s) * 4 + j] = a;
            int g = pair & 63;
            atomicAdd(&stats[g * 8 + j], a);
            atomicAdd(&stats[g * 8 + 4 + j], a * a);
        }
        __syncthreads();   // P7 done before next-iter zero of u
    }

    __threadfence();
    cg::this_grid().sync();
    __threadfence();

    // ================= quantum tail: blocks 0..B/256-1 ======================
    if (blk < (B >> 8)) {
        for (int i = t; i < 256; i += 256) Ush[i] = ((const float2*)Ug)[i];
        if (t < 8) smq[t] = 0.f;
        __syncthreads();
        {
            float v = stats[t] + stats[t + 256];     // j = t&7 preserved
            atomicAdd(&smq[t & 7], v);
        }
        __syncthreads();
        int s = blk * 256 + t;
        float4 fv = ((const float4*)feat)[s];
        float f[4] = {fv.x, fv.y, fv.z, fv.w};
        float cn[4], sn[4];
        float invB = 1.0f / (float)B;
        #pragma unroll
        for (int ww = 0; ww < 4; ww++) {
            float mean = smq[ww] * invB;
            float var  = smq[4 + ww] * invB - mean * mean;
            float fh = (f[ww] - mean) / sqrtf(var + B_EPS) * bn_g[ww] + bn_b[ww];
            cn[ww] = cosf(0.5f * fh);
            sn[ww] = sinf(0.5f * fh);
        }
        // encoded product state: s0_k = prod(c/s) * (-i)^popcount(k)
        float re0[16], im0[16];
        #pragma unroll
        for (int k = 0; k < 16; k++) {
            float mag = ((k & 8) ? sn[0] : cn[0]) * ((k & 4) ? sn[1] : cn[1]) *
                        ((k & 2) ? sn[2] : cn[2]) * ((k & 1) ? sn[3] : cn[3]);
            int m = __popc(k) & 3;
            re0[k] = (m == 0) ? mag : (m == 2) ? -mag : 0.f;
            im0[k] = (m == 1) ? -mag : (m == 3) ? mag : 0.f;
        }
        float o0 = 0.f, o1 = 0.f, o2 = 0.f, o3 = 0.f;
        #pragma unroll
        for (int r = 0; r < 16; r++) {
            float ar = 0.f, ai = 0.f;
            #pragma unroll
            for (int k = 0; k < 16; k++) {
                float2 uu = Ush[r * 16 + k];
                ar += uu.x * re0[k] - uu.y * im0[k];
                ai += uu.x * im0[k] + uu.y * re0[k];
            }
            float p = ar * ar + ai * ai;
            o0 += (r & 8) ? -p : p;
            o1 += (r & 4) ? -p : p;
            o2 += (r & 2) ? -p : p;
            o3 += (r & 1) ? -p : p;
        }
        float4 ov = {o0, o1, o2, o3};
        ((float4*)out)[s] = ov;
    }
}

// ---------------------------------------------------------------------------
extern "C" void kernel_launch(void* const* d_in, const int* in_sizes, int n_in,
                              void* d_out, int out_size, void* d_ws, size_t ws_size,
                              hipStream_t stream)
{
    const float* x   = (const float*)d_in[0];
    const float* c1w = (const float*)d_in[1];
    const float* c1b = (const float*)d_in[2];
    const float* c2w = (const float*)d_in[3];
    const float* c2b = (const float*)d_in[4];
    const float* f1w = (const float*)d_in[5];
    const float* f1b = (const float*)d_in[6];
    const float* f2w = (const float*)d_in[7];
    const float* f2b = (const float*)d_in[8];
    const float* bng = (const float*)d_in[9];
    const float* bnb = (const float*)d_in[10];
    const float* rl  = (const float*)d_in[11];
    float* out = (float*)d_out;

    int B = in_sizes[0] / 784;

    float* wsf   = (float*)d_ws;
    float* feat  = wsf;                          // B*4
    float* wT    = feat + (size_t)B * 4;         // 784*64
    float* U     = wT + 784 * 64;                // 512 (float2[256])
    float* stats = U + 512;                      // 512 (64 shards x 8)

    // co-resident grid size from live occupancy (grid-stride keeps any size
    // correct); 256 CUs on MI355X.
    int perCU = 0;
    hipOccupancyMaxActiveBlocksPerMultiprocessor(&perCU, mega_kernel, 256, 0);
    if (perCU < 1) perCU = 1;
    int nBlocks = perCU * 256;
    int npairs = B / 2;
    if (nBlocks > npairs) nBlocks = npairs;

    void* args[] = { (void*)&x, (void*)&c1w, (void*)&c1b, (void*)&c2w,
                     (void*)&c2b, (void*)&f1w, (void*)&f1b, (void*)&f2w,
                     (void*)&f2b, (void*)&bng, (void*)&bnb, (void*)&rl,
                     (void*)&out, (void*)&feat, (void*)&wT, (void*)&U,
                     (void*)&stats, (void*)&B };
    hipLaunchCooperativeKernel(mega_kernel, dim3(nBlocks), dim3(256),
                               args, 0, stream);
}

// Round 10
// 500.691 us; speedup vs baseline: 1.3073x; 1.3073x over previous
//
#include <hip/hip_runtime.h>
#include <hip/hip_bf16.h>
#include <hip/hip_cooperative_groups.h>

namespace cg = cooperative_groups;

// ---------------------------------------------------------------------------
// QuantumImageEncoder R10: R9's cooperative persistent kernel with the spill
// fixed: __launch_bounds__(256) only (R9's (256,4) forced the 64-VGPR tier ->
// conv2 spilled ~240 MB scratch to HBM; R7's identical conv code at plain
// (256) compiles to 76 VGPR, no spill). Everything else byte-identical to R9.
// ---------------------------------------------------------------------------

#define B_EPS 1e-5f

__global__ __launch_bounds__(256) void mega_kernel(
    const float* __restrict__ x,  const float* __restrict__ c1w,
    const float* __restrict__ c1b, const float* __restrict__ c2w,
    const float* __restrict__ c2b, const float* __restrict__ f1w,
    const float* __restrict__ f1b, const float* __restrict__ f2w,
    const float* __restrict__ f2bias, const float* __restrict__ bn_g,
    const float* __restrict__ bn_b, const float* __restrict__ rl,
    float* __restrict__ out, float* __restrict__ feat,
    float* __restrict__ wT, float* __restrict__ Ug,
    float* __restrict__ stats, int B)
{
    __shared__ union alignas(16) {
        float xin[2][30 * 32];     // padded 28x28, row stride 32, halo ring
        float flat[2][800];        // reused after conv1 (conv2 pooled output)
    } u;
    __shared__ alignas(16) float p1[2][8 * 292];   // [ch][row16][col18]+pad
    __shared__ float w1s[8][9], b1s[8], w2s[16][73], b2s[16];
    __shared__ float part[4][64];                  // fc1 partials per wave
    __shared__ float hs[2][64];                    // fc1 activations
    __shared__ float2 Ush[256];                    // U build / quantum U
    __shared__ float smq[8];                       // quantum reduced stats

    int t = threadIdx.x;
    int w = t >> 6, lane = t & 63;
    int blk = blockIdx.x, nb = gridDim.x;

    // ================= phase 0 =================
    if (blk == 0) {
        // ---- build U = G30*...*G1 into Ush, write Ug; zero 512-float stats
        int r = t >> 4, cc = t & 15;
        Ush[r * 16 + cc] = (r == cc) ? make_float2(1.f, 0.f) : make_float2(0.f, 0.f);
        stats[t] = 0.f;
        stats[t + 256] = 0.f;
        __syncthreads();
        for (int op = 0; op < 30; op++) {
            int kind = op & 3;               // 0=rx,1=ry,2=rz,3=cnot
            float2 cur = Ush[r * 16 + cc];
            float2 nv;
            if (kind == 3) {
                float2 pt = Ush[(r ^ 8) * 16 + cc];
                nv = (r & 1) ? pt : cur;
            } else {
                int m = 8 >> kind;
                float theta = rl[op - (op >> 2)];
                float ch = cosf(0.5f * theta), sh = sinf(0.5f * theta);
                float2 pt = Ush[(r ^ m) * 16 + cc];
                int br = (r & m) ? 1 : 0;
                float2 gc, gp;
                if (kind == 0)      { gc = make_float2(ch, 0.f);           gp = make_float2(0.f, -sh); }
                else if (kind == 1) { gc = make_float2(ch, 0.f);           gp = make_float2(br ? sh : -sh, 0.f); }
                else                { gc = make_float2(ch, br ? sh : -sh); gp = make_float2(0.f, 0.f); }
                nv.x = gc.x*cur.x - gc.y*cur.y + gp.x*pt.x - gp.y*pt.y;
                nv.y = gc.x*cur.y + gc.y*cur.x + gp.x*pt.y + gp.y*pt.x;
            }
            __syncthreads();
            Ush[r * 16 + cc] = nv;
            __syncthreads();
        }
        ((float2*)Ug)[t] = Ush[t];
    } else {
        // ---- transpose fc1_w -> wT[k*64+o], distributed over blocks 1..nb-1
        for (int id = (blk - 1) * 256 + t; id < 784 * 64; id += (nb - 1) * 256) {
            int k = id >> 6, o = id & 63;
            wT[id] = f1w[o * 784 + k];
        }
    }
    // ---- stage conv weights + zero p1 (once; interior rewritten each pair)
    {
        float4 z = make_float4(0.f, 0.f, 0.f, 0.f);
        float4* pz = (float4*)p1;
        for (int i = t; i < 2 * 8 * 292 / 4; i += 256) pz[i] = z;
    }
    if (t < 72) ((float*)w1s)[t] = c1w[t];
    if (t < 8)  b1s[t] = c1b[t];
    for (int i = t; i < 16 * 72; i += 256) w2s[i / 72][i % 72] = c2w[i];
    if (t < 16) b2s[t] = c2b[t];
    __syncthreads();

    __threadfence();
    cg::this_grid().sync();
    __threadfence();

    // ================= main loop: grid-stride over sample-pairs =============
    int npairs = B >> 1;
    for (int pair = blk; pair < npairs; pair += nb) {
        // ---- zero xin (flat aliased it last iteration; halo must be 0)
        {
            float4 z = make_float4(0.f, 0.f, 0.f, 0.f);
            float4* xz = (float4*)u.xin;
            for (int i = t; i < 2 * 30 * 32 / 4; i += 256) xz[i] = z;
        }
        __syncthreads();
        // ---- stage input (2 samples), shifted +1 for the zero halo
        {
            const float4* xg = (const float4*)(x + (size_t)pair * 2 * 784);
            for (int i = t; i < 392; i += 256) {
                float4 v = xg[i];
                int s = i / 196, q = (i - s * 196) * 4;
                float vv[4] = {v.x, v.y, v.z, v.w};
                #pragma unroll
                for (int j = 0; j < 4; j++) {
                    int p = q + j, rr = p / 28, cc2 = p - rr * 28;
                    u.xin[s][(rr + 1) * 32 + cc2 + 1] = vv[j];
                }
            }
        }
        __syncthreads();

        // ---- P2: conv1 + relu + pool -> p1   (wave=(s,h), lane=(ch,colgrp))
        {
            int s = w >> 1, h = w & 1;
            int c = lane >> 3, g = lane & 7;
            if (g < 7) {
                float wk[9];
                #pragma unroll
                for (int q = 0; q < 9; q++) wk[q] = w1s[c][q];
                float bias = b1s[c];
                const float* xb = &u.xin[s][4 * g];
                float* pout = &p1[s][c * 292];
                for (int ii = 0; ii < 7; ii++) {
                    int i = h * 7 + ii;                 // pooled row 0..13
                    const float* r = xb + 2 * i * 32;
                    float rv[4][6];
                    #pragma unroll
                    for (int dr = 0; dr < 4; dr++) {
                        float2 a = *(const float2*)(r + dr * 32);
                        float2 b = *(const float2*)(r + dr * 32 + 2);
                        float2 c2v = *(const float2*)(r + dr * 32 + 4);
                        rv[dr][0] = a.x;  rv[dr][1] = a.y;
                        rv[dr][2] = b.x;  rv[dr][3] = b.y;
                        rv[dr][4] = c2v.x; rv[dr][5] = c2v.y;
                    }
                    float o[2][4];
                    #pragma unroll
                    for (int dr = 0; dr < 2; dr++)
                        #pragma unroll
                        for (int j = 0; j < 4; j++) {
                            float acc = bias;
                            #pragma unroll
                            for (int ky = 0; ky < 3; ky++)
                                #pragma unroll
                                for (int kx = 0; kx < 3; kx++)
                                    acc = fmaf(wk[ky * 3 + kx], rv[dr + ky][j + kx], acc);
                            o[dr][j] = acc;
                        }
                    #pragma unroll
                    for (int jj = 0; jj < 2; jj++) {
                        float m = fmaxf(fmaxf(o[0][2 * jj], o[0][2 * jj + 1]),
                                        fmaxf(o[1][2 * jj], o[1][2 * jj + 1]));
                        pout[(i + 1) * 18 + 1 + 2 * g + jj] = fmaxf(m, 0.f);
                    }
                }
            }
        }
        __syncthreads();

        // ---- P3: conv2 + relu + pool -> u.flat (xin dead now)
        {
            int s = w >> 1, h = w & 1;
            int c2 = lane >> 2, g2 = lane & 3;
            int i0 = h * 4;
            float bias = b2s[c2];
            float acc[4][2][4];
            #pragma unroll
            for (int ii = 0; ii < 4; ii++)
                #pragma unroll
                for (int dr = 0; dr < 2; dr++)
                    #pragma unroll
                    for (int j = 0; j < 4; j++) acc[ii][dr][j] = bias;

            const float* pbase = &p1[s][4 * g2] + i0 * 2 * 18;
            for (int ci = 0; ci < 8; ci++) {
                float wk[9];
                #pragma unroll
                for (int q = 0; q < 9; q++) wk[q] = w2s[c2][ci * 9 + q];
                const float* pc_ = pbase + ci * 292;
                #pragma unroll
                for (int ii = 0; ii < 4; ii++) {
                    if (ii < 3 || h == 0) {
                        float rv[4][6];
                        #pragma unroll
                        for (int dr = 0; dr < 4; dr++) {
                            const float* rp = pc_ + (ii * 2 + dr) * 18;
                            float2 a = *(const float2*)rp;
                            float2 b = *(const float2*)(rp + 2);
                            float2 cc2 = *(const float2*)(rp + 4);
                            rv[dr][0] = a.x;  rv[dr][1] = a.y;
                            rv[dr][2] = b.x;  rv[dr][3] = b.y;
                            rv[dr][4] = cc2.x; rv[dr][5] = cc2.y;
                        }
                        #pragma unroll
                        for (int dr = 0; dr < 2; dr++)
                            #pragma unroll
                            for (int j = 0; j < 4; j++) {
                                float a2 = acc[ii][dr][j];
                                #pragma unroll
                                for (int ky = 0; ky < 3; ky++)
                                    #pragma unroll
                                    for (int kx = 0; kx < 3; kx++)
                                        a2 = fmaf(wk[ky * 3 + kx], rv[dr + ky][j + kx], a2);
                                acc[ii][dr][j] = a2;
                            }
                    }
                }
            }
            #pragma unroll
            for (int ii = 0; ii < 4; ii++) {
                if (ii < 3 || h == 0) {
                    int i = i0 + ii;
                    #pragma unroll
                    for (int jj = 0; jj < 2; jj++) {
                        int pc = 2 * g2 + jj;
                        if (pc < 7) {
                            float m = fmaxf(fmaxf(acc[ii][0][2 * jj], acc[ii][0][2 * jj + 1]),
                                            fmaxf(acc[ii][1][2 * jj], acc[ii][1][2 * jj + 1]));
                            u.flat[s][c2 * 49 + i * 7 + pc] = fmaxf(m, 0.f);
                        }
                    }
                }
            }
        }
        __syncthreads();

        // ---- P5: fc1 partials. wave=(s,k-half); lane=neuron.
        {
            int s = w >> 1, h2 = w & 1;
            const float* fl = u.flat[s];
            const float* wp = wT + lane;
            int k0 = h2 * 392;
            float a0 = 0.f, a1 = 0.f, a2 = 0.f, a3 = 0.f;
            for (int k = k0; k < k0 + 392; k += 4) {
                a0 = fmaf(fl[k    ], wp[(k    ) * 64], a0);
                a1 = fmaf(fl[k + 1], wp[(k + 1) * 64], a1);
                a2 = fmaf(fl[k + 2], wp[(k + 2) * 64], a2);
                a3 = fmaf(fl[k + 3], wp[(k + 3) * 64], a3);
            }
            part[w][lane] = (a0 + a1) + (a2 + a3);
        }
        __syncthreads();

        // ---- P6: combine halves + bias + relu
        if (t < 128) {
            int s = t >> 6, o = t & 63;
            float h = part[2 * s][o] + part[2 * s + 1][o] + f1b[o];
            hs[s][o] = fmaxf(h, 0.f);
        }
        __syncthreads();

        // ---- P7: fc2 + feat + sharded BN stats
        if (t < 8) {
            int s = t >> 2, j = t & 3;
            float a = f2bias[j];
            #pragma unroll
            for (int o = 0; o < 64; o++) a = fmaf(hs[s][o], f2w[j * 64 + o], a);
            feat[((size_t)pair * 2 + s) * 4 + j] = a;
            int g = pair & 63;
            atomicAdd(&stats[g * 8 + j], a);
            atomicAdd(&stats[g * 8 + 4 + j], a * a);
        }
        __syncthreads();   // P7 done before next-iter zero of u
    }

    __threadfence();
    cg::this_grid().sync();
    __threadfence();

    // ================= quantum tail: blocks 0..B/256-1 ======================
    if (blk < (B >> 8)) {
        for (int i = t; i < 256; i += 256) Ush[i] = ((const float2*)Ug)[i];
        if (t < 8) smq[t] = 0.f;
        __syncthreads();
        {
            float v = stats[t] + stats[t + 256];     // j = t&7 preserved
            atomicAdd(&smq[t & 7], v);
        }
        __syncthreads();
        int s = blk * 256 + t;
        float4 fv = ((const float4*)feat)[s];
        float f[4] = {fv.x, fv.y, fv.z, fv.w};
        float cn[4], sn[4];
        float invB = 1.0f / (float)B;
        #pragma unroll
        for (int ww = 0; ww < 4; ww++) {
            float mean = smq[ww] * invB;
            float var  = smq[4 + ww] * invB - mean * mean;
            float fh = (f[ww] - mean) / sqrtf(var + B_EPS) * bn_g[ww] + bn_b[ww];
            cn[ww] = cosf(0.5f * fh);
            sn[ww] = sinf(0.5f * fh);
        }
        // encoded product state: s0_k = prod(c/s) * (-i)^popcount(k)
        float re0[16], im0[16];
        #pragma unroll
        for (int k = 0; k < 16; k++) {
            float mag = ((k & 8) ? sn[0] : cn[0]) * ((k & 4) ? sn[1] : cn[1]) *
                        ((k & 2) ? sn[2] : cn[2]) * ((k & 1) ? sn[3] : cn[3]);
            int m = __popc(k) & 3;
            re0[k] = (m == 0) ? mag : (m == 2) ? -mag : 0.f;
            im0[k] = (m == 1) ? -mag : (m == 3) ? mag : 0.f;
        }
        float o0 = 0.f, o1 = 0.f, o2 = 0.f, o3 = 0.f;
        #pragma unroll
        for (int r = 0; r < 16; r++) {
            float ar = 0.f, ai = 0.f;
            #pragma unroll
            for (int k = 0; k < 16; k++) {
                float2 uu = Ush[r * 16 + k];
                ar += uu.x * re0[k] - uu.y * im0[k];
                ai += uu.x * im0[k] + uu.y * re0[k];
            }
            float p = ar * ar + ai * ai;
            o0 += (r & 8) ? -p : p;
            o1 += (r & 4) ? -p : p;
            o2 += (r & 2) ? -p : p;
            o3 += (r & 1) ? -p : p;
        }
        float4 ov = {o0, o1, o2, o3};
        ((float4*)out)[s] = ov;
    }
}

// ---------------------------------------------------------------------------
extern "C" void kernel_launch(void* const* d_in, const int* in_sizes, int n_in,
                              void* d_out, int out_size, void* d_ws, size_t ws_size,
                              hipStream_t stream)
{
    const float* x   = (const float*)d_in[0];
    const float* c1w = (const float*)d_in[1];
    const float* c1b = (const float*)d_in[2];
    const float* c2w = (const float*)d_in[3];
    const float* c2b = (const float*)d_in[4];
    const float* f1w = (const float*)d_in[5];
    const float* f1b = (const float*)d_in[6];
    const float* f2w = (const float*)d_in[7];
    const float* f2b = (const float*)d_in[8];
    const float* bng = (const float*)d_in[9];
    const float* bnb = (const float*)d_in[10];
    const float* rl  = (const float*)d_in[11];
    float* out = (float*)d_out;

    int B = in_sizes[0] / 784;

    float* wsf   = (float*)d_ws;
    float* feat  = wsf;                          // B*4
    float* wT    = feat + (size_t)B * 4;         // 784*64
    float* U     = wT + 784 * 64;                // 512 (float2[256])
    float* stats = U + 512;                      // 512 (64 shards x 8)

    // co-resident grid size from live occupancy (grid-stride keeps any size
    // correct); 256 CUs on MI355X.
    int perCU = 0;
    hipOccupancyMaxActiveBlocksPerMultiprocessor(&perCU, mega_kernel, 256, 0);
    if (perCU < 1) perCU = 1;
    int nBlocks = perCU * 256;
    int npairs = B / 2;
    if (nBlocks > npairs) nBlocks = npairs;

    void* args[] = { (void*)&x, (void*)&c1w, (void*)&c1b, (void*)&c2w,
                     (void*)&c2b, (void*)&f1w, (void*)&f1b, (void*)&f2w,
                     (void*)&f2b, (void*)&bng, (void*)&bnb, (void*)&rl,
                     (void*)&out, (void*)&feat, (void*)&wT, (void*)&U,
                     (void*)&stats, (void*)&B };
    hipLaunchCooperativeKernel(mega_kernel, dim3(nBlocks), dim3(256),
                               args, 0, stream);
}

// Round 11
// 226.551 us; speedup vs baseline: 2.8893x; 2.2101x over previous
//
#include <hip/hip_runtime.h>
#include <hip/hip_bf16.h>

// ---------------------------------------------------------------------------
// QuantumImageEncoder R11: R7 3-kernel structure (cooperative falsified in
// R9/R10) with two fixes:
//  1) fc scratch (part/hs) unioned into p1 (dead after conv2) -> LDS 33.3->31.4
//     KB -> 5 blocks/CU (R2's conv-proper occupancy).
//  2) fc1 uses R8's wT2[k4][64][4] float4 layout: 98 float4 global loads +
//     98 broadcast b128 LDS reads per thread (was 392 scalar loads).
// ---------------------------------------------------------------------------

#define B_EPS 1e-5f

// ---------------- prep: build U (block 0, zero 512-float stats) +
// ----------------       reformat fc1_w -> wT2[k4][o][j] (blocks 1..196) ----
__global__ void prep_kernel(const float* __restrict__ rl,
                            const float* __restrict__ f1w,
                            float* __restrict__ Uout,
                            float* __restrict__ wT2,
                            float* __restrict__ stats)
{
    if (blockIdx.x == 0) {
        __shared__ float2 U[16][16];
        int t = threadIdx.x;                 // 256 threads
        int r = t >> 4, cc = t & 15;
        U[r][cc] = (r == cc) ? make_float2(1.f, 0.f) : make_float2(0.f, 0.f);
        stats[t] = 0.f;                      // 512-float sharded stats
        stats[t + 256] = 0.f;
        __syncthreads();
        for (int op = 0; op < 30; op++) {
            int kind = op & 3;               // 0=rx,1=ry,2=rz,3=cnot ; wire = op%4
            float2 cur = U[r][cc];
            float2 nv;
            if (kind == 3) {
                float2 part = U[r ^ 8][cc];  // control wire3 (bit 1), target wire0 (bit 8)
                nv = (r & 1) ? part : cur;
            } else {
                int m = 8 >> kind;           // wire w=kind -> bit (3-w)
                float theta = rl[op - (op >> 2)];
                float ch = cosf(0.5f * theta), sh = sinf(0.5f * theta);
                float2 part = U[r ^ m][cc];
                int br = (r & m) ? 1 : 0;
                float2 gc, gp;
                if (kind == 0)      { gc = make_float2(ch, 0.f);           gp = make_float2(0.f, -sh); }
                else if (kind == 1) { gc = make_float2(ch, 0.f);           gp = make_float2(br ? sh : -sh, 0.f); }
                else                { gc = make_float2(ch, br ? sh : -sh); gp = make_float2(0.f, 0.f); }
                nv.x = gc.x*cur.x - gc.y*cur.y + gp.x*part.x - gp.y*part.y;
                nv.y = gc.x*cur.y + gc.y*cur.x + gp.x*part.y + gp.y*part.x;
            }
            __syncthreads();
            U[r][cc] = nv;
            __syncthreads();
        }
        ((float2*)Uout)[t] = U[r][cc];
    } else {
        int id = (blockIdx.x - 1) * 256 + threadIdx.x;
        if (id < 784 * 64) {
            int k = id >> 6, o = id & 63;
            // wT2 float index = (k4*64 + o)*4 + (k&3)
            wT2[(((k >> 2) * 64 + o) << 2) + (k & 3)] = f1w[o * 784 + k];
        }
    }
}

// ---------------- conv backbone + fused fc: 2 samples / block, 4 waves ------
__global__ __launch_bounds__(256) void conv_kernel(
    const float* __restrict__ x,  const float* __restrict__ c1w,
    const float* __restrict__ c1b, const float* __restrict__ c2w,
    const float* __restrict__ c2b, const float* __restrict__ wT2,
    const float* __restrict__ f1b, const float* __restrict__ f2w,
    const float* __restrict__ f2bias, float* __restrict__ feat,
    float* __restrict__ stats)
{
    __shared__ union alignas(16) {
        float xin[2][30 * 32];     // padded 28x28, row stride 32, halo ring
        float flat[2][800];        // reused after conv1 (conv2 pooled output)
    } u;
    __shared__ union alignas(16) {
        float p1[2][8 * 292];      // [ch][row16][col18]+pad, stride 292
        struct { float part[4][64]; float hs[2][64]; } fc;   // p1 dead after P3
    } pu;
    __shared__ float w1s[8][9], b1s[8], w2s[16][73], b2s[16];

    int t = threadIdx.x;
    int w = t >> 6, lane = t & 63;

    // ---- P1: zero xin + p1 (halo correctness), load conv weights
    {
        float4 z = make_float4(0.f, 0.f, 0.f, 0.f);
        float4* xz = (float4*)u.xin;
        for (int i = t; i < 2 * 30 * 32 / 4; i += 256) xz[i] = z;
        float4* pz = (float4*)pu.p1;
        for (int i = t; i < 2 * 8 * 292 / 4; i += 256) pz[i] = z;
    }
    if (t < 72) ((float*)w1s)[t] = c1w[t];
    if (t < 8)  b1s[t] = c1b[t];
    for (int i = t; i < 16 * 72; i += 256) w2s[i / 72][i % 72] = c2w[i];
    if (t < 16) b2s[t] = c2b[t];
    __syncthreads();

    // ---- stage input (2 samples), shifted +1 for the zero halo
    {
        const float4* xg = (const float4*)(x + (size_t)blockIdx.x * 2 * 784);
        for (int i = t; i < 392; i += 256) {
            float4 v = xg[i];
            int s = i / 196, q = (i - s * 196) * 4;
            float vv[4] = {v.x, v.y, v.z, v.w};
            #pragma unroll
            for (int j = 0; j < 4; j++) {
                int p = q + j, rr = p / 28, cc = p - rr * 28;
                u.xin[s][(rr + 1) * 32 + cc + 1] = vv[j];
            }
        }
    }
    __syncthreads();

    // ---- P2: conv1 + relu + pool -> p1   (wave=(s,h), lane=(ch,colgroup))
    {
        int s = w >> 1, h = w & 1;
        int c = lane >> 3, g = lane & 7;
        if (g < 7) {
            float wk[9];
            #pragma unroll
            for (int q = 0; q < 9; q++) wk[q] = w1s[c][q];
            float bias = b1s[c];
            const float* xb = &u.xin[s][4 * g];
            float* pout = &pu.p1[s][c * 292];
            for (int ii = 0; ii < 7; ii++) {
                int i = h * 7 + ii;                     // pooled row 0..13
                const float* r = xb + 2 * i * 32;
                float rv[4][6];
                #pragma unroll
                for (int dr = 0; dr < 4; dr++) {
                    float2 a = *(const float2*)(r + dr * 32);
                    float2 b = *(const float2*)(r + dr * 32 + 2);
                    float2 c2v = *(const float2*)(r + dr * 32 + 4);
                    rv[dr][0] = a.x;  rv[dr][1] = a.y;
                    rv[dr][2] = b.x;  rv[dr][3] = b.y;
                    rv[dr][4] = c2v.x; rv[dr][5] = c2v.y;
                }
                float o[2][4];
                #pragma unroll
                for (int dr = 0; dr < 2; dr++)
                    #pragma unroll
                    for (int j = 0; j < 4; j++) {
                        float acc = bias;
                        #pragma unroll
                        for (int ky = 0; ky < 3; ky++)
                            #pragma unroll
                            for (int kx = 0; kx < 3; kx++)
                                acc = fmaf(wk[ky * 3 + kx], rv[dr + ky][j + kx], acc);
                        o[dr][j] = acc;
                    }
                #pragma unroll
                for (int jj = 0; jj < 2; jj++) {
                    float m = fmaxf(fmaxf(o[0][2 * jj], o[0][2 * jj + 1]),
                                    fmaxf(o[1][2 * jj], o[1][2 * jj + 1]));
                    pout[(i + 1) * 18 + 1 + 2 * g + jj] = fmaxf(m, 0.f);
                }
            }
        }
    }
    __syncthreads();

    // ---- P3: conv2 + relu + pool -> u.flat (xin dead now)
    {
        int s = w >> 1, h = w & 1;
        int c2 = lane >> 2, g2 = lane & 3;
        int i0 = h * 4;                                 // h=0: i 0..3, h=1: i 4..6
        float bias = b2s[c2];
        float acc[4][2][4];
        #pragma unroll
        for (int ii = 0; ii < 4; ii++)
            #pragma unroll
            for (int dr = 0; dr < 2; dr++)
                #pragma unroll
                for (int j = 0; j < 4; j++) acc[ii][dr][j] = bias;

        const float* pbase = &pu.p1[s][4 * g2] + i0 * 2 * 18;
        for (int ci = 0; ci < 8; ci++) {
            float wk[9];
            #pragma unroll
            for (int q = 0; q < 9; q++) wk[q] = w2s[c2][ci * 9 + q];
            const float* pc_ = pbase + ci * 292;
            #pragma unroll
            for (int ii = 0; ii < 4; ii++) {
                if (ii < 3 || h == 0) {
                    float rv[4][6];
                    #pragma unroll
                    for (int dr = 0; dr < 4; dr++) {
                        const float* rp = pc_ + (ii * 2 + dr) * 18;
                        float2 a = *(const float2*)rp;
                        float2 b = *(const float2*)(rp + 2);
                        float2 cc = *(const float2*)(rp + 4);
                        rv[dr][0] = a.x;  rv[dr][1] = a.y;
                        rv[dr][2] = b.x;  rv[dr][3] = b.y;
                        rv[dr][4] = cc.x; rv[dr][5] = cc.y;
                    }
                    #pragma unroll
                    for (int dr = 0; dr < 2; dr++)
                        #pragma unroll
                        for (int j = 0; j < 4; j++) {
                            float a2 = acc[ii][dr][j];
                            #pragma unroll
                            for (int ky = 0; ky < 3; ky++)
                                #pragma unroll
                                for (int kx = 0; kx < 3; kx++)
                                    a2 = fmaf(wk[ky * 3 + kx], rv[dr + ky][j + kx], a2);
                            acc[ii][dr][j] = a2;
                        }
                }
            }
        }
        #pragma unroll
        for (int ii = 0; ii < 4; ii++) {
            if (ii < 3 || h == 0) {
                int i = i0 + ii;
                #pragma unroll
                for (int jj = 0; jj < 2; jj++) {
                    int pc = 2 * g2 + jj;
                    if (pc < 7) {
                        float m = fmaxf(fmaxf(acc[ii][0][2 * jj], acc[ii][0][2 * jj + 1]),
                                        fmaxf(acc[ii][1][2 * jj], acc[ii][1][2 * jj + 1]));
                        u.flat[s][c2 * 49 + i * 7 + pc] = fmaxf(m, 0.f);
                    }
                }
            }
        }
    }
    __syncthreads();   // p1 dead from here; pu.fc live

    // ---- P5: fc1 partials. wave=(s,k-half); lane=neuron. float4 weight
    // loads (wT2[k4][64][4]) + broadcast b128 LDS activation reads.
    {
        int s = w >> 1, h2 = w & 1;
        const float* fl = u.flat[s];
        const float4* wp4 = (const float4*)wT2 + lane;   // + g*64 per k4-group
        int g0 = h2 * 98;
        float a0 = 0.f, a1 = 0.f;
        #pragma unroll 2
        for (int g = g0; g < g0 + 98; g += 2) {
            float4 wv0 = wp4[(size_t)g * 64];
            float4 f0 = *(const float4*)&fl[4 * g];
            float4 wv1 = wp4[(size_t)(g + 1) * 64];
            float4 f1 = *(const float4*)&fl[4 * (g + 1)];
            a0 = fmaf(f0.x, wv0.x, fmaf(f0.y, wv0.y, fmaf(f0.z, wv0.z, fmaf(f0.w, wv0.w, a0))));
            a1 = fmaf(f1.x, wv1.x, fmaf(f1.y, wv1.y, fmaf(f1.z, wv1.z, fmaf(f1.w, wv1.w, a1))));
        }
        pu.fc.part[w][lane] = a0 + a1;
    }
    __syncthreads();

    // ---- P6: combine halves + bias + relu
    if (t < 128) {
        int s = t >> 6, o = t & 63;
        float h = pu.fc.part[2 * s][o] + pu.fc.part[2 * s + 1][o] + f1b[o];
        pu.fc.hs[s][o] = fmaxf(h, 0.f);
    }
    __syncthreads();

    // ---- P7: fc2 + feat + sharded BN stats
    if (t < 8) {
        int s = t >> 2, j = t & 3;
        float a = f2bias[j];
        #pragma unroll
        for (int o = 0; o < 64; o++) a = fmaf(pu.fc.hs[s][o], f2w[j * 64 + o], a);
        feat[((size_t)blockIdx.x * 2 + s) * 4 + j] = a;
        int g = blockIdx.x & 63;
        atomicAdd(&stats[g * 8 + j], a);
        atomicAdd(&stats[g * 8 + 4 + j], a * a);
    }
}

// ---------------- BN + encoder + U matvec + PauliZ measure ------------------
__global__ __launch_bounds__(128) void quantum_kernel(
    const float* __restrict__ feat, const float* __restrict__ Ug,
    const float* __restrict__ stats, const float* __restrict__ bn_g,
    const float* __restrict__ bn_b, float* __restrict__ out, int B)
{
    __shared__ float2 Us[256];
    __shared__ float sm[8];
    int t = threadIdx.x;                  // 128 threads
    for (int i = t; i < 256; i += 128) Us[i] = ((const float2*)Ug)[i];
    if (t < 8) sm[t] = 0.f;
    __syncthreads();
    {   // parallel gather of 64 shards x 8 (index mod 8 preserved by +128)
        float v = stats[t] + stats[t + 128] + stats[t + 256] + stats[t + 384];
        atomicAdd(&sm[t & 7], v);
    }
    __syncthreads();
    int s = blockIdx.x * 128 + t;
    float4 fv = ((const float4*)feat)[s];
    float f[4] = {fv.x, fv.y, fv.z, fv.w};
    float cn[4], sn[4];
    float invB = 1.0f / (float)B;
    #pragma unroll
    for (int w = 0; w < 4; w++) {
        float mean = sm[w] * invB;
        float var  = sm[4 + w] * invB - mean * mean;
        float fh = (f[w] - mean) / sqrtf(var + B_EPS) * bn_g[w] + bn_b[w];
        cn[w] = cosf(0.5f * fh);
        sn[w] = sinf(0.5f * fh);
    }
    // encoded product state: s0_k = prod(c/s) * (-i)^popcount(k)
    float re0[16], im0[16];
    #pragma unroll
    for (int k = 0; k < 16; k++) {
        float mag = ((k & 8) ? sn[0] : cn[0]) * ((k & 4) ? sn[1] : cn[1]) *
                    ((k & 2) ? sn[2] : cn[2]) * ((k & 1) ? sn[3] : cn[3]);
        int m = __popc(k) & 3;
        re0[k] = (m == 0) ? mag : (m == 2) ? -mag : 0.f;
        im0[k] = (m == 1) ? -mag : (m == 3) ? mag : 0.f;
    }
    float o0 = 0.f, o1 = 0.f, o2 = 0.f, o3 = 0.f;
    #pragma unroll
    for (int r = 0; r < 16; r++) {
        float ar = 0.f, ai = 0.f;
        #pragma unroll
        for (int k = 0; k < 16; k++) {
            float2 uu = Us[r * 16 + k];
            ar += uu.x * re0[k] - uu.y * im0[k];
            ai += uu.x * im0[k] + uu.y * re0[k];
        }
        float p = ar * ar + ai * ai;
        o0 += (r & 8) ? -p : p;
        o1 += (r & 4) ? -p : p;
        o2 += (r & 2) ? -p : p;
        o3 += (r & 1) ? -p : p;
    }
    float4 ov = {o0, o1, o2, o3};
    ((float4*)out)[s] = ov;
}

// ---------------------------------------------------------------------------
extern "C" void kernel_launch(void* const* d_in, const int* in_sizes, int n_in,
                              void* d_out, int out_size, void* d_ws, size_t ws_size,
                              hipStream_t stream)
{
    const float* x   = (const float*)d_in[0];
    const float* c1w = (const float*)d_in[1];
    const float* c1b = (const float*)d_in[2];
    const float* c2w = (const float*)d_in[3];
    const float* c2b = (const float*)d_in[4];
    const float* f1w = (const float*)d_in[5];
    const float* f1b = (const float*)d_in[6];
    const float* f2w = (const float*)d_in[7];
    const float* f2b = (const float*)d_in[8];
    const float* bng = (const float*)d_in[9];
    const float* bnb = (const float*)d_in[10];
    const float* rl  = (const float*)d_in[11];
    float* out = (float*)d_out;

    int B = in_sizes[0] / 784;

    float* wsf   = (float*)d_ws;
    float* feat  = wsf;                          // B*4
    float* wT2   = feat + (size_t)B * 4;         // 784*64 (as [k4][64][4])
    float* U     = wT2 + 784 * 64;               // 512 (float2[256])
    float* stats = U + 512;                      // 512 (64 shards x 8)

    prep_kernel<<<197, 256, 0, stream>>>(rl, f1w, U, wT2, stats);
    conv_kernel<<<B / 2, 256, 0, stream>>>(x, c1w, c1b, c2w, c2b, wT2,
                                           f1b, f2w, f2b, feat, stats);
    quantum_kernel<<<B / 128, 128, 0, stream>>>(feat, U, stats, bng, bnb, out, B);
}